// Round 1
// baseline (7798.409 us; speedup 1.0000x reference)
//
#include <hip/hip_runtime.h>

// Packed-LSTM (B=64, S=2048, H=512, V=25) + final linear head.
// Strategy: sort batches by length (stable, descending) inside the kernel;
// 4 groups of 16 batches run in lockstep. Each group uses 16 workgroups,
// each owning 32 hidden units (128 gate rows). W_hh slice lives in VGPRs as
// bf16 MFMA B-fragments (loaded once). Per step: MFMA [16x512]@[512x128],
// LSTM cell update in fp32, h exchanged between the group's WGs through LLC
// with agent-scope atomics + per-WG monotonic step flags (parity double
// buffer). Output = h_last . fc_w + fc_b, accumulated with atomicAdd.

#define VOCAB 25
#define HIDDEN 512
#define BATCH 64
#define SEQ 2048
#define GB 16    // batches per group
#define NG 4     // groups
#define WPG 16   // workgroups per group
#define HSL 32   // hidden units per WG
#define RWG 128  // gate rows per WG = 4*HSL
#define NTHREADS 256

typedef short s16x8 __attribute__((ext_vector_type(8)));
typedef float f32x4 __attribute__((ext_vector_type(4)));

__device__ inline unsigned short f2bf(float x) {
  unsigned u = __float_as_uint(x);
  u += 0x7fffu + ((u >> 16) & 1u);  // RNE
  return (unsigned short)(u >> 16);
}
__device__ inline float sigf(float x) { return 1.0f / (1.0f + __expf(-x)); }
__device__ inline float tanh_fast(float x) { return 2.0f / (1.0f + __expf(-2.0f * x)) - 1.0f; }

__global__ void prep_kernel(int* flags, float* out) {
  const int i = blockIdx.x * blockDim.x + threadIdx.x;
  if (i < NG * WPG * 32) flags[i] = 0;
  if (i < BATCH) out[i] = 0.f;
}

__global__ __launch_bounds__(NTHREADS, 1) void lstm_persistent(
    const int* __restrict__ tokens, const int* __restrict__ lengths,
    const float* __restrict__ W_ih, const float* __restrict__ W_hh,
    const float* __restrict__ b_ih, const float* __restrict__ b_hh,
    const float* __restrict__ fc_w, const float* __restrict__ fc_b,
    float* __restrict__ out, int* flags, unsigned short* hglob) {
  const int tid = threadIdx.x;
  const int bid = blockIdx.x;
  // XCD-aware swizzle: group g uses blocks with bid%8 in {2g,2g+1} -> 2 XCDs/group.
  const int x = bid & 7;
  const int g = x >> 1;                       // group 0..3
  const int w = ((bid >> 3) << 1) | (x & 1);  // wg-in-group 0..15

  __shared__ __align__(16) unsigned short hbuf[GB][HIDDEN + 8];  // bf16 h, padded
  __shared__ float gatesb[GB][RWG + 4];
  __shared__ float xgt[VOCAB][RWG + 4];  // per-slice input projection table
  __shared__ int toks[GB];
  __shared__ int lenAll[BATCH];
  __shared__ int order_[BATCH];
  __shared__ int gIdx[GB];
  __shared__ int gLen[GB];

  if (tid < BATCH) lenAll[tid] = lengths[tid];
  __syncthreads();
  if (tid < BATCH) {  // stable argsort(-lengths): rank by count
    const int L = lenAll[tid];
    int r = 0;
    for (int j = 0; j < BATCH; ++j) {
      const int lj = lenAll[j];
      r += ((lj > L) || (lj == L && j < tid)) ? 1 : 0;
    }
    order_[r] = tid;
  }
  __syncthreads();
  if (tid < GB) {
    const int oi = order_[g * GB + tid];
    gIdx[tid] = oi;
    gLen[tid] = lenAll[oi];
  }
  for (int i = tid; i < GB * (HIDDEN + 8); i += NTHREADS)
    ((unsigned short*)hbuf)[i] = 0;  // h0 = 0
  for (int i = tid; i < VOCAB * RWG; i += NTHREADS) {
    const int v = i / RWG, rl = i % RWG;
    const int rg = (rl >> 5) * HIDDEN + w * HSL + (rl & 31);
    xgt[v][rl] = W_ih[rg * VOCAB + v] + b_ih[rg] + b_hh[rg];
  }
  __syncthreads();

  const int T = gLen[0];  // group maxlen (sorted descending)
  const int lane = tid & 63;
  const int wv = tid >> 6;
  const int m16 = lane & 15;
  const int quad = lane >> 4;

  // B fragments (bf16 W_hh slice) resident in VGPRs: wave wv owns ntiles {wv, wv+4}.
  // B[k][n] layout: n = lane&15, k = quad*8 + j within each K=32 chunk.
  s16x8 Bf[2][16];
#pragma unroll
  for (int nti = 0; nti < 2; ++nti) {
    const int nt = wv + 4 * nti;
    const int rl = nt * 16 + m16;  // local gate-row 0..127
    const int rg = (rl >> 5) * HIDDEN + w * HSL + (rl & 31);
    const float* wr = W_hh + (size_t)rg * HIDDEN;
#pragma unroll
    for (int kt = 0; kt < 16; ++kt) {
      const float* p = wr + kt * 32 + quad * 8;
#pragma unroll
      for (int e = 0; e < 8; ++e) Bf[nti][kt][e] = (short)f2bf(p[e]);
    }
  }

  // Cell state: thread (cb,cs) owns hidden units jj0,jj1 of batch cb.
  const int cb = tid >> 4;
  const int cs = tid & 15;
  const int jj0 = 2 * cs, jj1 = 2 * cs + 1;
  const int myLen = gLen[cb];
  const int* tokRow = tokens + (size_t)gIdx[tid < GB ? tid : 0] * SEQ;
  int* myFlag = flags + (g * WPG + w) * 32;
  const size_t hgStride = (size_t)GB * HIDDEN;  // shorts per group buffer

  float c0 = 0.f, c1 = 0.f, h0 = 0.f, h1 = 0.f;

  for (int t = 0; t < T; ++t) {
    if (tid < GB) toks[tid] = tokRow[t];
    if (t > 0) {
      if (tid < WPG) {  // wait for all 16 slices of step t
        int* fp = flags + (g * WPG + tid) * 32;
        while (__hip_atomic_load(fp, __ATOMIC_ACQUIRE, __HIP_MEMORY_SCOPE_AGENT) < t)
          __builtin_amdgcn_s_sleep(1);
      }
      __syncthreads();
      // stage h (bf16) from LLC into LDS
      const unsigned long long* src =
          (const unsigned long long*)(hglob + ((size_t)(t & 1) * NG + g) * hgStride);
      const int sb = tid & 15, seg = tid >> 4;
      const unsigned long long* sp = src + sb * (HIDDEN / 4) + seg * 8;
      unsigned long long tmp[8];
#pragma unroll
      for (int r2 = 0; r2 < 8; ++r2)
        tmp[r2] = __hip_atomic_load((unsigned long long*)(sp + r2), __ATOMIC_RELAXED,
                                    __HIP_MEMORY_SCOPE_AGENT);
      unsigned long long* dst = (unsigned long long*)&hbuf[sb][seg * 32];
#pragma unroll
      for (int r2 = 0; r2 < 8; ++r2) dst[r2] = tmp[r2];
    }
    __syncthreads();

    // gates slice = h[16x512] @ Wslice^T[512x128] via MFMA 16x16x32 bf16
    f32x4 acc0 = {0.f, 0.f, 0.f, 0.f};
    f32x4 acc1 = {0.f, 0.f, 0.f, 0.f};
#pragma unroll
    for (int kt = 0; kt < 16; ++kt) {
      const s16x8 A = *(const s16x8*)&hbuf[m16][kt * 32 + quad * 8];
      acc0 = __builtin_amdgcn_mfma_f32_16x16x32_bf16(A, Bf[0][kt], acc0, 0, 0, 0);
      acc1 = __builtin_amdgcn_mfma_f32_16x16x32_bf16(A, Bf[1][kt], acc1, 0, 0, 0);
    }
    // D layout: col(n)=lane&15, row(m)=quad*4+v
#pragma unroll
    for (int v = 0; v < 4; ++v) {
      gatesb[quad * 4 + v][wv * 16 + m16] = acc0[v];
      gatesb[quad * 4 + v][(wv + 4) * 16 + m16] = acc1[v];
    }
    __syncthreads();

    // LSTM cell update (fp32), frozen past sequence end
    const int tok = toks[cb];
    const float pi0 = gatesb[cb][jj0] + xgt[tok][jj0];
    const float pf0 = gatesb[cb][32 + jj0] + xgt[tok][32 + jj0];
    const float pg0 = gatesb[cb][64 + jj0] + xgt[tok][64 + jj0];
    const float po0 = gatesb[cb][96 + jj0] + xgt[tok][96 + jj0];
    const float pi1 = gatesb[cb][jj1] + xgt[tok][jj1];
    const float pf1 = gatesb[cb][32 + jj1] + xgt[tok][32 + jj1];
    const float pg1 = gatesb[cb][64 + jj1] + xgt[tok][64 + jj1];
    const float po1 = gatesb[cb][96 + jj1] + xgt[tok][96 + jj1];
    if (t < myLen) {
      const float i0 = sigf(pi0), f0 = sigf(pf0), g0 = tanh_fast(pg0), o0 = sigf(po0);
      c0 = f0 * c0 + i0 * g0;
      h0 = o0 * tanh_fast(c0);
      const float i1 = sigf(pi1), f1 = sigf(pf1), g1 = tanh_fast(pg1), o1 = sigf(po1);
      c1 = f1 * c1 + i1 * g1;
      h1 = o1 * tanh_fast(c1);
    }
    if (t + 1 < T) {  // publish h slice (bf16, write-through to LLC)
      const unsigned val = (unsigned)f2bf(h0) | ((unsigned)f2bf(h1) << 16);
      unsigned* hp = (unsigned*)(hglob + ((size_t)((t + 1) & 1) * NG + g) * hgStride +
                                 (size_t)cb * HIDDEN + w * HSL + jj0);
      __hip_atomic_store(hp, val, __ATOMIC_RELAXED, __HIP_MEMORY_SCOPE_AGENT);
    }
    __syncthreads();  // all lanes' h stores drained (vmcnt) before flag post
    if (t + 1 < T && tid == 0)
      __hip_atomic_store(myFlag, t + 1, __ATOMIC_RELEASE, __HIP_MEMORY_SCOPE_AGENT);
  }

  // out[p] = h . fc_w + fc_b, p = sorted position
  float part = h0 * fc_w[w * HSL + jj0] + h1 * fc_w[w * HSL + jj1];
  part += __shfl_down(part, 8, 16);
  part += __shfl_down(part, 4, 16);
  part += __shfl_down(part, 2, 16);
  part += __shfl_down(part, 1, 16);
  if (cs == 0) {
    if (w == 0) part += fc_b[0];
    atomicAdd(&out[g * GB + cb], part);
  }
}

extern "C" void kernel_launch(void* const* d_in, const int* in_sizes, int n_in,
                              void* d_out, int out_size, void* d_ws, size_t ws_size,
                              hipStream_t stream) {
  (void)in_sizes; (void)n_in; (void)out_size; (void)ws_size;
  const int* tokens = (const int*)d_in[0];
  const int* lengths = (const int*)d_in[1];
  const float* W_ih = (const float*)d_in[2];
  const float* W_hh = (const float*)d_in[3];
  const float* b_ih = (const float*)d_in[4];
  const float* b_hh = (const float*)d_in[5];
  const float* fc_w = (const float*)d_in[6];
  const float* fc_b = (const float*)d_in[7];
  float* out = (float*)d_out;
  int* flags = (int*)d_ws;                                       // 8 KB (padded flags)
  unsigned short* hglob = (unsigned short*)((char*)d_ws + 8192); // 128 KB h double-buffer

  prep_kernel<<<8, 256, 0, stream>>>(flags, out);
  lstm_persistent<<<64, NTHREADS, 0, stream>>>(tokens, lengths, W_ih, W_hh, b_ih, b_hh,
                                               fc_w, fc_b, out, flags, hglob);
}